// Round 1
// 551.384 us; speedup vs baseline: 1.0448x; 1.0448x over previous
//
#include <hip/hip_runtime.h>
#include <math.h>

#define HW   4096
#define DKC  256
#define DVC  516
#define LM   32
#define NB   4
#define P1   8     // pixels per block, kernel 1

// XCD-aware chunked swizzle (8 XCDs, round-robin dispatch of blockIdx):
// XCD k receives bid ∈ {k, k+8, k+16, ...}; remap so each XCD owns a
// CONTIGUOUS chunk of the logical work index. This co-locates the 4 blocks
// that share each 128B L2 line of kbuf/fc (32B per 8-px block) on ONE XCD,
// turning 3/4 redundant HBM fetches into L2 hits. Bijective since both
// grids are multiples of 8.
__device__ __forceinline__ int xcd_swizzle(int bid, int nwg) {
    int chunk = nwg >> 3;
    return (bid & 7) * chunk + (bid >> 3);
}

// Kernel 1: q-projection + scores + softmax -> attn[4][32][4096] (f32, in ws)
// Block: 256 threads, covers P1=8 consecutive pixels for ALL 4 batches (so
// key_buffer is streamed exactly once). LDS: fc tile (32KB) aliased with the
// q tile after projection, + 4KB scores. 36KB -> 2 blocks/CU so one block's
// projection VALU overlaps the other block's k-streaming.
__global__ __launch_bounds__(256) void k_attn(const float* __restrict__ fc,
                                              const float* __restrict__ Qw,
                                              const float* __restrict__ kbuf,
                                              float* __restrict__ attn,
                                              float temp) {
    __shared__ float smem[8192 + 1024];   // fc[c][px][b] -> later q[(b*8+px)][d]; +scores
    float* sc_t = smem + 8192;            // [4][32][8]
    const int t   = threadIdx.x;
    const int px0 = xcd_swizzle(blockIdx.x, gridDim.x) * P1;

    // Phase 0: fc[b][c][px0..px0+7] -> smem[c*32 + px*4 + b]
    #pragma unroll
    for (int i = 0; i < 32; ++i) {
        int f  = i * 256 + t;        // flat over [b][c][px]
        int b  = f >> 11;
        int c  = (f >> 3) & 255;
        int px = f & 7;
        smem[c * 32 + px * 4 + b] = fc[(b * DKC + c) * HW + px0 + px];
    }
    __syncthreads();

    // Phase 1: projection. thread = (dgrp, px): owns q[b=0..3][d0..d0+7]
    const int px   = t & 7;
    const int dgrp = t >> 3;          // 0..31
    const int d0   = dgrp * 8;
    float acc[4][8];
    #pragma unroll
    for (int b = 0; b < 4; ++b)
        #pragma unroll
        for (int i = 0; i < 8; ++i) acc[b][i] = 0.0f;

    for (int c = 0; c < 256; ++c) {
        float4 fcv = *(const float4*)&smem[c * 32 + px * 4];      // 4 batches, LDS broadcast
        float4 q0  = *(const float4*)&Qw[c * 256 + d0];
        float4 q1  = *(const float4*)&Qw[c * 256 + d0 + 4];
        float fq[8] = {q0.x, q0.y, q0.z, q0.w, q1.x, q1.y, q1.z, q1.w};
        float fb[4] = {fcv.x, fcv.y, fcv.z, fcv.w};
        #pragma unroll
        for (int b = 0; b < 4; ++b)
            #pragma unroll
            for (int i = 0; i < 8; ++i)
                acc[b][i] += fb[b] * fq[i];
    }
    __syncthreads();   // all fc reads done; safe to overwrite smem with q

    // q layout: smem[(b*8+px)*256 + d]
    #pragma unroll
    for (int b = 0; b < 4; ++b) {
        *(float4*)&smem[(b * 8 + px) * 256 + d0]     = make_float4(acc[b][0], acc[b][1], acc[b][2], acc[b][3]);
        *(float4*)&smem[(b * 8 + px) * 256 + d0 + 4] = make_float4(acc[b][4], acc[b][5], acc[b][6], acc[b][7]);
    }
    __syncthreads();

    // Phase 2: scores. thread = (m, px); dot over all 256 d.
    const int m = t >> 3;             // 0..31
    float s[4] = {0.f, 0.f, 0.f, 0.f};
    for (int d = 0; d < 256; d += 4) {
        float kv0 = kbuf[(m * DKC + d + 0) * HW + px0 + px];
        float kv1 = kbuf[(m * DKC + d + 1) * HW + px0 + px];
        float kv2 = kbuf[(m * DKC + d + 2) * HW + px0 + px];
        float kv3 = kbuf[(m * DKC + d + 3) * HW + px0 + px];
        #pragma unroll
        for (int b = 0; b < 4; ++b) {
            float4 qv = *(const float4*)&smem[(b * 8 + px) * 256 + d];
            s[b] += qv.x * kv0 + qv.y * kv1 + qv.z * kv2 + qv.w * kv3;
        }
    }
    #pragma unroll
    for (int b = 0; b < 4; ++b) sc_t[(b * 32 + m) * 8 + px] = s[b] * temp;
    __syncthreads();

    // Phase 3: softmax over m (32 threads, one per (b,px))
    if (t < 32) {
        int b = t >> 3, p = t & 7;
        float mx = -1e30f;
        for (int mm = 0; mm < 32; ++mm) mx = fmaxf(mx, sc_t[(b * 32 + mm) * 8 + p]);
        float sum = 0.f;
        for (int mm = 0; mm < 32; ++mm) sum += expf(sc_t[(b * 32 + mm) * 8 + p] - mx);
        float inv = 1.0f / sum;
        for (int mm = 0; mm < 32; ++mm)
            attn[(b * 32 + mm) * HW + px0 + p] = expf(sc_t[(b * 32 + mm) * 8 + p] - mx) * inv;
    }
}

// Kernel 2: out[b,c,px] = fm + 0.5 * sum_m attn[b,m,px] * v[m,c,px]
// Block: 64-px chunk x 12-c chunk, all m, all b. attn tile (32KB) in LDS.
// All global streams are 64 consecutive px per wave -> 256B coalesced.
// Swizzled so each XCD covers all px for a few c-chunks: the shared attn
// tiles and full 16KB vbuf rows stay within one XCD's L2.
__global__ __launch_bounds__(256) void k_out(const float* __restrict__ vbuf,
                                             const float* __restrict__ fm,
                                             const float* __restrict__ attn,
                                             float* __restrict__ out) {
    __shared__ float a_lds[4 * 32 * 64];  // [b][m][px]
    const int t   = threadIdx.x;
    const int sw  = xcd_swizzle(blockIdx.x, gridDim.x);
    const int px0 = (sw & 63) * 64;
    const int c0  = (sw >> 6) * 12;

    #pragma unroll
    for (int i = 0; i < 32; ++i) {
        int f  = i * 256 + t;             // flat over [b][m][px]
        int b  = f >> 11;
        int m  = (f >> 6) & 31;
        int px = f & 63;
        a_lds[f] = attn[(b * 32 + m) * HW + px0 + px];
    }
    __syncthreads();

    const int px   = t & 63;
    const int cidx = t >> 6;              // 0..3, each owns 3 channels
    float acc[4][3] = {};
    for (int m = 0; m < 32; ++m) {
        float a0 = a_lds[(0 * 32 + m) * 64 + px];
        float a1 = a_lds[(1 * 32 + m) * 64 + px];
        float a2 = a_lds[(2 * 32 + m) * 64 + px];
        float a3 = a_lds[(3 * 32 + m) * 64 + px];
        #pragma unroll
        for (int j = 0; j < 3; ++j) {
            int c = c0 + cidx * 3 + j;
            float vv = vbuf[(m * DVC + c) * HW + px0 + px];
            acc[0][j] += a0 * vv;
            acc[1][j] += a1 * vv;
            acc[2][j] += a2 * vv;
            acc[3][j] += a3 * vv;
        }
    }
    #pragma unroll
    for (int j = 0; j < 3; ++j) {
        int c = c0 + cidx * 3 + j;
        #pragma unroll
        for (int b = 0; b < 4; ++b) {
            int idx = (b * DVC + c) * HW + px0 + px;
            out[idx] = fm[idx] + 0.5f * acc[b][j];
        }
    }
}

extern "C" void kernel_launch(void* const* d_in, const int* in_sizes, int n_in,
                              void* d_out, int out_size, void* d_ws, size_t ws_size,
                              hipStream_t stream) {
    const float* fc = (const float*)d_in[0];
    const float* fm = (const float*)d_in[1];
    const float* kb = (const float*)d_in[2];
    const float* vb = (const float*)d_in[3];
    const float* Qw = (const float*)d_in[4];
    // K (d_in[5]) and V (d_in[6]) projections are discarded by the [-32:]
    // truncation in the reference (4 new + 32 buffer -> last 32 = buffer).
    float* out  = (float*)d_out;
    float* attn = (float*)d_ws;   // 4*32*4096 f32 = 2 MB

    const float temp = (float)(log(32.0 * 4096.0 + 4096.0) / log(2.0) / 16.0);

    k_attn<<<HW / P1, 256, 0, stream>>>(fc, Qw, kb, attn, temp);
    k_out<<<64 * (DVC / 12), 256, 0, stream>>>(vb, fm, attn, out);
}